// Round 7
// baseline (3626.120 us; speedup 1.0000x reference)
//
#include <hip/hip_runtime.h>
#include <math.h>

#define TB 512
#define TT 256
#define DD 256

typedef float f32x4 __attribute__((ext_vector_type(4)));

// ---------------- workspace layout (float offsets) ----------------
#define WS_WF   0u            // fused Wf = composer_W @ writer_W  [512][1024] fp32
#define WS_BF   524288u       // fused bias [1024]
#define WS_HP   525312u       // h publish, double-buffered [2][32][256]
#define WS_PAR  541696u       // partials [32 batches][8 slices][260] (256 P + max + sum)
#define PS      260
#define WS_WHP  608256u       // wh publish [32][256]
#define WS_BAR  616448u       // ints: tagsA[8][32][32]=0, tagsB@8192, lcnt@16384, magic@16416,
                              //       xcnt@16448+i*8, gok@16512
#define WS_FLOATS 633024u

// ---------------- LDS layout (float offsets) ----------------
// acts use padded chunk strides: writer 48->52 floats/chunk, reader 32->36.
#define O_MEM   0        // mem slice fp32 [32 rows][260]
#define S_MEM   260
#define O_WACT  8320     // writer act [4 bl][832]: [o|m_rt|wh] at awk positions
#define S_WACT  832
#define O_RACT  11648    // reader act [4 bl][576]: [x|h] at ark positions
#define S_RACT  576
#define O_WZ    13952    // [4][36]
#define O_RZ    14096    // [4][36]
#define O_SS    14240    // [32]
#define O_SE    14272    // [32]
#define O_WC    14304    // [32]
#define O_RC    14336    // [32]
#define O_WB    14368    // [32]
#define O_RB    14400    // [32]
#define O_RJ    14432    // [4 bl][8 j]
#define O_MS    14464    // [4 bl][8 j][2]
#define O_XR    14528    // ints: xcd, rank, flag
#define DYN_LDS_BYTES 131072   // 128 KB: forces 1 WG/CU; front 24832 fl reused as weight-staging temp

__device__ __forceinline__ float hsig(float x) { return fminf(fmaxf(0.2f*x + 0.5f, 0.f), 1.f); }
__device__ __forceinline__ float ftanh(float x) {
  const float a = fminf(fabsf(x), 15.f);
  const float e = __expf(2.f * a);
  return copysignf((e - 1.f) / (e + 1.f), x);
}
__device__ __forceinline__ int awk(int k) { return (k / 48) * 52 + (k % 48); }
__device__ __forceinline__ int ark(int k) { return (k >> 5) * 36 + (k & 31); }

// ---- scoped cross-WG primitives: lx=true -> sc0 (XCD L2); lx=false -> sc0 sc1 (agent/L3)
__device__ __forceinline__ void stI(int* p, int v, bool lx) {
  if (lx) asm volatile("global_store_dword %0, %1, off sc0" :: "v"(p), "v"(v) : "memory");
  else    asm volatile("global_store_dword %0, %1, off sc0 sc1" :: "v"(p), "v"(v) : "memory");
}
__device__ __forceinline__ int ldI(const int* p, bool lx) {
  int t;
  if (lx) asm volatile("global_load_dword %0, %1, off sc0\n\ts_waitcnt vmcnt(0)" : "=v"(t) : "v"(p) : "memory");
  else    asm volatile("global_load_dword %0, %1, off sc0 sc1\n\ts_waitcnt vmcnt(0)" : "=v"(t) : "v"(p) : "memory");
  return t;
}
__device__ __forceinline__ void stF(float* p, float v, bool lx) {
  if (lx) asm volatile("global_store_dword %0, %1, off sc0" :: "v"(p), "v"(v) : "memory");
  else    asm volatile("global_store_dword %0, %1, off sc0 sc1" :: "v"(p), "v"(v) : "memory");
}
__device__ __forceinline__ void stF4(float* p, f32x4 v, bool lx) {
  if (lx) asm volatile("global_store_dwordx4 %0, %1, off sc0" :: "v"(p), "v"(v) : "memory");
  else    asm volatile("global_store_dwordx4 %0, %1, off sc0 sc1" :: "v"(p), "v"(v) : "memory");
}
__device__ __forceinline__ void ld2x4(const float* p1, const float* p2, f32x4& a, f32x4& b, bool lx) {
  if (lx) asm volatile(
    "global_load_dwordx4 %0, %2, off sc0\n\t"
    "global_load_dwordx4 %1, %3, off sc0\n\t"
    "s_waitcnt vmcnt(0)" : "=&v"(a), "=&v"(b) : "v"(p1), "v"(p2) : "memory");
  else asm volatile(
    "global_load_dwordx4 %0, %2, off sc0 sc1\n\t"
    "global_load_dwordx4 %1, %3, off sc0 sc1\n\t"
    "s_waitcnt vmcnt(0)" : "=&v"(a), "=&v"(b) : "v"(p1), "v"(p2) : "memory");
}

// producer: drain data publishes, then tag
__device__ __forceinline__ void tag_store(int* tp, int v, bool lx) {
  asm volatile("s_waitcnt vmcnt(0) lgkmcnt(0)" ::: "memory");
  __syncthreads();
  if (threadIdx.x == 0) stI(tp, v, lx);
}
__device__ __forceinline__ void tag_spin(const int* tags, int v, bool lx) {
  if (threadIdx.x < 32) {     // 32 lanes poll 32 tag lines
    int sp = 0;
    for (;;) {
      const int t = ldI(&tags[threadIdx.x * 32], lx);
      if (__all(t == v)) break;
      __builtin_amdgcn_s_sleep(1);
      if (++sp > (1 << 16)) break;   // fail loud (wrong answer), never hang
    }
  }
  __syncthreads();
}
// fenced device-scope barrier (one-time uses only)
__device__ __forceinline__ void barrier_fenced(int* cnt, int target) {
  __syncthreads();
  if (threadIdx.x == 0) {
    __threadfence();
    __hip_atomic_fetch_add(cnt, 1, __ATOMIC_RELAXED, __HIP_MEMORY_SCOPE_AGENT);
    int sp = 0;
    while (__hip_atomic_load(cnt, __ATOMIC_RELAXED, __HIP_MEMORY_SCOPE_AGENT) < target) {
      if (++sp > (1 << 20)) break;
    }
    __threadfence();
  }
  __syncthreads();
}

__global__ void __launch_bounds__(TB, 2) nse_kernel(
    const float* __restrict__ x,
    const float* __restrict__ rW, const float* __restrict__ rU, const float* __restrict__ rb,
    const float* __restrict__ wW, const float* __restrict__ wU, const float* __restrict__ wb,
    const float* __restrict__ cW, const float* __restrict__ cb,
    float* __restrict__ out, float* __restrict__ ws)
{
  extern __shared__ float sm[];
  const int tid = threadIdx.x;
  const int w = blockIdx.x;

  float* Wf   = ws + WS_WF;
  float* bfv  = ws + WS_BF;
  float* hpub = ws + WS_HP;
  float* par  = ws + WS_PAR;
  float* whp  = ws + WS_WHP;
  int*   bars = (int*)(ws + WS_BAR);
  int* lcnt   = &bars[16384];
  int* magic  = &bars[16416];
  int* xr     = (int*)&sm[O_XR];

  // ---- one-time init gate (ws poisoned 0xAA every launch) ----
  if (w == 0 && tid == 0) {
    __hip_atomic_store(lcnt, 0, __ATOMIC_RELAXED, __HIP_MEMORY_SCOPE_AGENT);
    for (int i = 0; i < 8; i++)
      __hip_atomic_store(&bars[16448 + i*8], 0, __ATOMIC_RELAXED, __HIP_MEMORY_SCOPE_AGENT);
    __hip_atomic_store(&bars[16512], 1, __ATOMIC_RELAXED, __HIP_MEMORY_SCOPE_AGENT);  // gok
    __hip_atomic_store(magic, 1357911, __ATOMIC_RELEASE, __HIP_MEMORY_SCOPE_AGENT);
  }
  if (tid == 0) {
    int sp = 0;
    while (__hip_atomic_load(magic, __ATOMIC_ACQUIRE, __HIP_MEMORY_SCOPE_AGENT) != 1357911) {
      if (++sp > (1 << 20)) break;
    }
  }
  __syncthreads();

  // ================= fold: Wf = cW @ wW (32k x 64n per WG), bf = cb@wW + wb =================
  {
    const int kt = w >> 4, nt = w & 15;
    const int r = tid >> 4, c4 = (tid & 15) * 4;
    float a0 = 0.f, a1 = 0.f, a2 = 0.f, a3 = 0.f;
    for (int jc = 0; jc < 512; jc += 32) {
      for (int u = tid; u < 1024; u += TB) {
        int rr = u >> 5, jj = u & 31;
        sm[rr*33 + jj] = cW[(32*kt + rr)*512 + jc + jj];
      }
      {
        int jj = tid >> 4, cc = (tid & 15) * 4;
        const f32x4 v = *(const f32x4*)&wW[(jc + jj)*1024 + 64*nt + cc];
        float* d = &sm[1056 + jj*68 + cc];
        d[0] = v.x; d[1] = v.y; d[2] = v.z; d[3] = v.w;
      }
      __syncthreads();
      #pragma unroll 8
      for (int j = 0; j < 32; j++) {
        const float a = sm[r*33 + j];
        const float* wv = &sm[1056 + j*68 + c4];
        a0 += a*wv[0]; a1 += a*wv[1]; a2 += a*wv[2]; a3 += a*wv[3];
      }
      __syncthreads();
    }
    float* d = &Wf[(32*kt + r)*1024 + 64*nt + c4];
    d[0] = a0; d[1] = a1; d[2] = a2; d[3] = a3;
  }
  if (w >= 16 && w < 32) {   // bias fold
    __syncthreads();
    const int base = (w - 16) * 64;
    const int c = tid & 63, jq = tid >> 6;
    float p = 0.f;
    for (int j = 64*jq; j < 64*jq + 64; j++) p += cb[j] * wW[j*1024 + base + c];
    sm[jq*68 + c] = p;
    __syncthreads();
    if (tid < 64) {
      float s = wb[base + tid];
      for (int j = 0; j < 8; j++) s += sm[j*68 + tid];
      bfv[base + tid] = s;
    }
  }
  barrier_fenced(lcnt, 256);

  // ================= XCD grouping + validation + protocol self-test =================
  {
    int xcd;
    asm volatile("s_getreg_b32 %0, hwreg(HW_REG_XCC_ID)" : "=s"(xcd));
    if (tid == 0) {
      const int rk = __hip_atomic_fetch_add(&bars[16448 + (xcd & 7)*8], 1,
                                            __ATOMIC_RELAXED, __HIP_MEMORY_SCOPE_AGENT);
      xr[0] = xcd & 7;
      xr[1] = rk;
    }
  }
  barrier_fenced(lcnt, 512);
  if (tid == 0) {
    int all32 = 1;
    for (int i = 0; i < 8; i++) {
      const int c = __hip_atomic_load(&bars[16448 + i*8], __ATOMIC_RELAXED, __HIP_MEMORY_SCOPE_AGENT);
      if (c != 32) all32 = 0;
    }
    xr[2] = all32;
  }
  __syncthreads();
  const int cnt_ok = xr[2];                  // uniform across ALL WGs
  const int g = cnt_ok ? xr[0] : (w >> 5);
  const int m = cnt_ok ? xr[1] : (w & 31);
  bool l2 = false;
  int* tagsA = &bars[g * 1024];
  int* tagsB = &bars[8192 + g * 1024];
  int* myA   = &tagsA[m * 32];
  int* myB   = &tagsB[m * 32];
  if (cnt_ok) {   // live test of the L2-scope tag protocol; any stale read -> fallback
    int* tvp = (int*)(ws + WS_PAR);          // scratch (overwritten at s=1)
    if (tid == 0) stI(&tvp[(g*32 + m)*32], 0x5A000000 + (g << 8) + m, true);
    asm volatile("s_waitcnt vmcnt(0) lgkmcnt(0)" ::: "memory");
    __syncthreads();
    if (tid == 0) stI(myA, 7777, true);
    if (tid < 32) {
      int sp = 0, to = 0;
      for (;;) {
        const int t = ldI(&tagsA[tid * 32], true);
        if (__all(t == 7777)) break;
        __builtin_amdgcn_s_sleep(1);
        if (++sp > (1 << 13)) { to = 1; break; }
      }
      const int v = ldI(&tvp[(g*32 + tid)*32], true);
      const int good = (!to) && (v == 0x5A000000 + (g << 8) + (int)tid);
      if (tid == 0 && !__all(good))
        __hip_atomic_store(&bars[16512], 0, __ATOMIC_RELAXED, __HIP_MEMORY_SCOPE_AGENT);
    }
    barrier_fenced(lcnt, 768);
    if (tid == 0)
      xr[2] = __hip_atomic_load(&bars[16512], __ATOMIC_RELAXED, __HIP_MEMORY_SCOPE_AGENT);
    __syncthreads();
    l2 = (xr[2] == 1);
  }
  const int b0  = g * 4;
  const int blm = m >> 3;
  const int isl = m & 7;
  const int bmy = b0 + blm;

  // thread roles for the GEMVs: col cl(32) x k-chunk q(16); bl looped
  const int q  = tid & 15;
  const int cl = tid >> 4;
  const int Ccol = (cl >> 3)*256 + 8*m + (cl & 7);

  // ================= weights -> VGPRs (fp32), via coalesced LDS temp =================
  float wrw[48], wrr[32];
  for (int u = tid; u < 6144; u += TB) {     // writer [Wf|wU] col slice -> tmp[col][768] str 776
    const int k = u >> 3, rem = u & 7, gate = rem >> 1, hf = rem & 1;
    const int col0 = gate*256 + 8*m + 4*hf;
    const f32x4 v = (k < 512) ? *(const f32x4*)&Wf[(size_t)k*1024 + col0]
                              : *(const f32x4*)&wU[(size_t)(k-512)*1024 + col0];
    const int c2 = gate*8 + 4*hf;
    sm[(c2+0)*776 + k] = v.x; sm[(c2+1)*776 + k] = v.y;
    sm[(c2+2)*776 + k] = v.z; sm[(c2+3)*776 + k] = v.w;
  }
  __syncthreads();
  #pragma unroll
  for (int kk = 0; kk < 48; kk += 4) {
    const f32x4 v = *(const f32x4*)&sm[cl*776 + q*48 + kk];
    wrw[kk] = v.x; wrw[kk+1] = v.y; wrw[kk+2] = v.z; wrw[kk+3] = v.w;
  }
  __syncthreads();
  for (int u = tid; u < 4096; u += TB) {     // reader [rW|rU] -> tmp[col][512] str 520
    const int k = u >> 3, rem = u & 7, gate = rem >> 1, hf = rem & 1;
    const int col0 = gate*256 + 8*m + 4*hf;
    const f32x4 v = (k < 256) ? *(const f32x4*)&rW[(size_t)k*1024 + col0]
                              : *(const f32x4*)&rU[(size_t)(k-256)*1024 + col0];
    const int c2 = gate*8 + 4*hf;
    sm[(c2+0)*520 + k] = v.x; sm[(c2+1)*520 + k] = v.y;
    sm[(c2+2)*520 + k] = v.z; sm[(c2+3)*520 + k] = v.w;
  }
  __syncthreads();
  #pragma unroll
  for (int kk = 0; kk < 32; kk += 4) {
    const f32x4 v = *(const f32x4*)&sm[cl*520 + q*32 + kk];
    wrr[kk] = v.x; wrr[kk+1] = v.y; wrr[kk+2] = v.z; wrr[kk+3] = v.w;
  }
  __syncthreads();

  // ================= state staging =================
  for (int u = tid; u < 2048; u += TB) {     // mem slice = x[bmy][32*isl..][:]
    const int r = u >> 6, d4 = (u & 63) * 4;
    *(f32x4*)&sm[O_MEM + r*S_MEM + d4] =
        *(const f32x4*)&x[((size_t)bmy*TT + 32*isl + r)*DD + d4];
  }
  for (int u = tid; u < 5632; u += TB) sm[O_WACT + u] = 0.f;   // zero WACT+RACT
  if (tid < 32) {
    sm[O_WB + tid] = bfv[(tid >> 3)*256 + 8*m + (tid & 7)];
    sm[O_RB + tid] = rb[(tid >> 3)*256 + 8*m + (tid & 7)];
    sm[O_WC + tid] = 0.f;
    sm[O_RC + tid] = 0.f;
  }
  __syncthreads();
  if (tid < 256) {   // x_0
    const int bl = tid >> 6, d4 = (tid & 63) * 4;
    *(f32x4*)&sm[O_RACT + bl*S_RACT + ark(d4)] =
        *(const f32x4*)&x[(size_t)(b0+bl)*TT*DD + d4];
  }
  __syncthreads();

  // ================= merged loop: reader step s (s<=255), writer step t=s-1 (s>=1) =================
  for (int s = 0; s <= TT; s++) {
    // ---- consume tagB(s-1): h_{s-1} + wh_{s-2} (one batched RT) ----
    if (s >= 1) {
      tag_spin(tagsB, s - 1, l2);
      if (tid < 256) {
        const int bl = tid >> 6, d4 = (tid & 63) * 4;
        f32x4 vh, vw;
        ld2x4(&hpub[(size_t)((s-1)&1)*8192 + (b0+bl)*256 + d4],
              &whp[(b0+bl)*256 + d4], vh, vw, l2);
        *(f32x4*)&sm[O_RACT + bl*S_RACT + ark(256 + d4)] = vh;   // reader h-in / W1 o
        *(f32x4*)&sm[O_WACT + bl*S_WACT + awk(d4)]       = vh;   // writer GEMV o
        if (s >= 2)
          *(f32x4*)&sm[O_WACT + bl*S_WACT + awk(512 + d4)] = vw; // writer wh-in + mem upd
      }
    }
    __syncthreads();

    // ---- W1 (s>=1): fused lazy mem-update (wh_{s-2}, z_{s-2}) + scores vs o_{s-1} ----
    if (s >= 1) {
      const int r = tid >> 4, tk = tid & 15;
      float* mrow = &sm[O_MEM + r*S_MEM + 16*tk];
      const float* orow = &sm[O_RACT + blm*S_RACT + ark(256 + 16*tk)];
      float acc = 0.f;
      if (s >= 2) {
        const float zr = sm[O_SE + r] * sm[O_RJ + blm*8 + isl];
        const float omz = 1.f - zr;
        const float* hrow = &sm[O_WACT + blm*S_WACT + awk(512 + 16*tk)];
        #pragma unroll
        for (int i2 = 0; i2 < 16; i2 += 4) {
          f32x4 mv = *(f32x4*)(mrow + i2);
          const f32x4 hv = *(const f32x4*)(hrow + i2);
          const f32x4 ov = *(const f32x4*)(orow + i2);
          mv.x = mv.x*omz + hv.x*zr;  mv.y = mv.y*omz + hv.y*zr;
          mv.z = mv.z*omz + hv.z*zr;  mv.w = mv.w*omz + hv.w*zr;
          *(f32x4*)(mrow + i2) = mv;
          acc += mv.x*ov.x + mv.y*ov.y + mv.z*ov.z + mv.w*ov.w;
        }
      } else {
        #pragma unroll
        for (int i2 = 0; i2 < 16; i2 += 4) {
          const f32x4 mv = *(const f32x4*)(mrow + i2);
          const f32x4 ov = *(const f32x4*)(orow + i2);
          acc += mv.x*ov.x + mv.y*ov.y + mv.z*ov.z + mv.w*ov.w;
        }
      }
      acc += __shfl_xor(acc, 1, 64); acc += __shfl_xor(acc, 2, 64);
      acc += __shfl_xor(acc, 4, 64); acc += __shfl_xor(acc, 8, 64);
      if (tk == 0) sm[O_SS + r] = acc;
    }
    __syncthreads();
    if (s >= 1 && tid < 32) {   // local softmax over my 32 rows; publish (max,sum)
      const float sc = sm[O_SS + tid];
      float mx = sc;
      mx = fmaxf(mx, __shfl_xor(mx, 1, 64)); mx = fmaxf(mx, __shfl_xor(mx, 2, 64));
      mx = fmaxf(mx, __shfl_xor(mx, 4, 64)); mx = fmaxf(mx, __shfl_xor(mx, 8, 64));
      mx = fmaxf(mx, __shfl_xor(mx, 16, 64));
      const float e = __expf(sc - mx);
      float su = e;
      su += __shfl_xor(su, 1, 64); su += __shfl_xor(su, 2, 64); su += __shfl_xor(su, 4, 64);
      su += __shfl_xor(su, 8, 64); su += __shfl_xor(su, 16, 64);
      sm[O_SE + tid] = e;
      if (tid == 0) {
        stF(&par[((size_t)bmy*8 + isl)*PS + 256], mx, l2);
        stF(&par[((size_t)bmy*8 + isl)*PS + 257], su, l2);
      }
    }
    __syncthreads();
    // ---- W2 (s>=1): P_isl[d] = sum_r e_r mem[r][d]; publish; tagA ----
    if (s >= 1) {
      const int dblk = tid >> 3, rh = tid & 7;
      f32x4 p; p.x = 0.f; p.y = 0.f; p.z = 0.f; p.w = 0.f;
      #pragma unroll
      for (int i = 0; i < 4; i++) {
        const int rr = 4*rh + i;
        const float e = sm[O_SE + rr];
        const f32x4 mv = *(const f32x4*)&sm[O_MEM + rr*S_MEM + 4*dblk];
        p.x += e*mv.x; p.y += e*mv.y; p.z += e*mv.z; p.w += e*mv.w;
      }
      p.x += __shfl_xor(p.x,1,64); p.x += __shfl_xor(p.x,2,64); p.x += __shfl_xor(p.x,4,64);
      p.y += __shfl_xor(p.y,1,64); p.y += __shfl_xor(p.y,2,64); p.y += __shfl_xor(p.y,4,64);
      p.z += __shfl_xor(p.z,1,64); p.z += __shfl_xor(p.z,2,64); p.z += __shfl_xor(p.z,4,64);
      p.w += __shfl_xor(p.w,1,64); p.w += __shfl_xor(p.w,2,64); p.w += __shfl_xor(p.w,4,64);
      if (rh == 0) stF4(&par[((size_t)bmy*8 + isl)*PS + 4*dblk], p, l2);
      tag_store(myA, s, l2);
    } else {
      __syncthreads();
    }

    // ---- slack: reader GEMV (register weights) + LSTM + h publish ----
    if (s <= TT-1) {
      #pragma unroll
      for (int bl = 0; bl < 4; bl++) {
        const float* ar = &sm[O_RACT + bl*S_RACT + q*36];
        float a = 0.f;
        #pragma unroll
        for (int kk = 0; kk < 32; kk += 4) {
          const f32x4 av = *(const f32x4*)(ar + kk);
          a += wrr[kk]*av.x + wrr[kk+1]*av.y + wrr[kk+2]*av.z + wrr[kk+3]*av.w;
        }
        a += __shfl_xor(a, 1, 64); a += __shfl_xor(a, 2, 64);
        a += __shfl_xor(a, 4, 64); a += __shfl_xor(a, 8, 64);
        if (q == 0) sm[O_RZ + bl*36 + cl] = a + sm[O_RB + cl];
      }
    }
    __syncthreads();
    if (s <= TT-1 && tid < 32) {
      const int bl = tid >> 3, dl = tid & 7;
      const float zi = sm[O_RZ + bl*36 + dl];
      const float zf = sm[O_RZ + bl*36 + 8 + dl];
      const float zg = sm[O_RZ + bl*36 + 16 + dl];
      const float zo = sm[O_RZ + bl*36 + 24 + dl];
      const float cn = hsig(zf)*sm[O_RC + tid] + hsig(zi)*ftanh(zg);
      sm[O_RC + tid] = cn;
      stF(&hpub[(size_t)(s&1)*8192 + (b0+bl)*256 + 8*m + dl], hsig(zo)*ftanh(cn), l2);
    }

    if (s >= 1) {
      tag_spin(tagsA, s, l2);
      // ---- combine: ONE RT for 8 P-slices + (max,sum) ----
      f32x4 v0,v1,v2,v3,v4,v5,v6,v7;
      float msv = 0.f;
      int bl = 0, d4 = 0;
      if (tid < 256) {
        bl = tid >> 6; d4 = (tid & 63) * 4;
        const float* p0 = &par[((size_t)(b0+bl)*8 + 0)*PS + d4];
        const float* p4 = p0 + 4*PS;
        const int idx = tid & 63;
        const float* msp = &par[((size_t)(b0 + (idx>>4))*8 + ((idx>>1)&7))*PS + 256 + (idx&1)];
        if (l2) asm volatile(
          "global_load_dwordx4 %0, %9, off sc0\n\t"
          "global_load_dwordx4 %1, %9, off offset:1040 sc0\n\t"
          "global_load_dwordx4 %2, %9, off offset:2080 sc0\n\t"
          "global_load_dwordx4 %3, %9, off offset:3120 sc0\n\t"
          "global_load_dwordx4 %4, %10, off sc0\n\t"
          "global_load_dwordx4 %5, %10, off offset:1040 sc0\n\t"
          "global_load_dwordx4 %6, %10, off offset:2080 sc0\n\t"
          "global_load_dwordx4 %7, %10, off offset:3120 sc0\n\t"
          "global_load_dword   %8, %11, off sc0\n\t"
          "s_waitcnt vmcnt(0)"
          : "=&v"(v0),"=&v"(v1),"=&v"(v2),"=&v"(v3),
            "=&v"(v4),"=&v"(v5),"=&v"(v6),"=&v"(v7),"=&v"(msv)
          : "v"(p0), "v"(p4), "v"(msp) : "memory");
        else asm volatile(
          "global_load_dwordx4 %0, %9, off sc0 sc1\n\t"
          "global_load_dwordx4 %1, %9, off offset:1040 sc0 sc1\n\t"
          "global_load_dwordx4 %2, %9, off offset:2080 sc0 sc1\n\t"
          "global_load_dwordx4 %3, %9, off offset:3120 sc0 sc1\n\t"
          "global_load_dwordx4 %4, %10, off sc0 sc1\n\t"
          "global_load_dwordx4 %5, %10, off offset:1040 sc0 sc1\n\t"
          "global_load_dwordx4 %6, %10, off offset:2080 sc0 sc1\n\t"
          "global_load_dwordx4 %7, %10, off offset:3120 sc0 sc1\n\t"
          "global_load_dword   %8, %11, off sc0 sc1\n\t"
          "s_waitcnt vmcnt(0)"
          : "=&v"(v0),"=&v"(v1),"=&v"(v2),"=&v"(v3),
            "=&v"(v4),"=&v"(v5),"=&v"(v6),"=&v"(v7),"=&v"(msv)
          : "v"(p0), "v"(p4), "v"(msp) : "memory");
      }
      if (tid < 64) sm[O_MS + tid] = msv;   // [bl][j][h] == idx
      __syncthreads();
      if (tid < 4) {
        const int b2 = tid;
        float M = sm[O_MS + b2*16];
        for (int j = 1; j < 8; j++) M = fmaxf(M, sm[O_MS + b2*16 + 2*j]);
        float tot = 0.f, f0[8];
        for (int j = 0; j < 8; j++) {
          f0[j] = __expf(sm[O_MS + b2*16 + 2*j] - M);
          tot += f0[j] * sm[O_MS + b2*16 + 2*j + 1];
        }
        const float inv = 1.f / tot;
        for (int j = 0; j < 8; j++) sm[O_RJ + b2*8 + j] = f0[j]*inv;
      }
      __syncthreads();
      if (tid < 256) {   // m_rt -> writer act
        const float* rj = &sm[O_RJ + bl*8];
        f32x4 a;
        a.x = rj[0]*v0.x + rj[1]*v1.x + rj[2]*v2.x + rj[3]*v3.x
            + rj[4]*v4.x + rj[5]*v5.x + rj[6]*v6.x + rj[7]*v7.x;
        a.y = rj[0]*v0.y + rj[1]*v1.y + rj[2]*v2.y + rj[3]*v3.y
            + rj[4]*v4.y + rj[5]*v5.y + rj[6]*v6.y + rj[7]*v7.y;
        a.z = rj[0]*v0.z + rj[1]*v1.z + rj[2]*v2.z + rj[3]*v3.z
            + rj[4]*v4.z + rj[5]*v5.z + rj[6]*v6.z + rj[7]*v7.z;
        a.w = rj[0]*v0.w + rj[1]*v1.w + rj[2]*v2.w + rj[3]*v3.w
            + rj[4]*v4.w + rj[5]*v5.w + rj[6]*v6.w + rj[7]*v7.w;
        *(f32x4*)&sm[O_WACT + bl*S_WACT + awk(256 + d4)] = a;
      }
      __syncthreads();
      // ---- writer gates GEMV (register weights, k-ascending chunks, tree-reduced) ----
      {
        #pragma unroll
        for (int bl2 = 0; bl2 < 4; bl2++) {
          const float* aw = &sm[O_WACT + bl2*S_WACT + q*52];
          float a = 0.f;
          #pragma unroll
          for (int kk = 0; kk < 48; kk += 4) {
            const f32x4 av = *(const f32x4*)(aw + kk);
            a += wrw[kk]*av.x + wrw[kk+1]*av.y + wrw[kk+2]*av.z + wrw[kk+3]*av.w;
          }
          a += __shfl_xor(a, 1, 64); a += __shfl_xor(a, 2, 64);
          a += __shfl_xor(a, 4, 64); a += __shfl_xor(a, 8, 64);
          if (q == 0) sm[O_WZ + bl2*36 + cl] = a + sm[O_WB + cl];
        }
      }
      __syncthreads();
      if (tid < 32) {   // writer LSTM update + publish wh (or out at last step)
        const int bl2 = tid >> 3, dl = tid & 7;
        const float zi = sm[O_WZ + bl2*36 + dl];
        const float zf = sm[O_WZ + bl2*36 + 8 + dl];
        const float zg = sm[O_WZ + bl2*36 + 16 + dl];
        const float zo = sm[O_WZ + bl2*36 + 24 + dl];
        const float cn = hsig(zf)*sm[O_WC + tid] + hsig(zi)*ftanh(zg);
        sm[O_WC + tid] = cn;
        const float hn = hsig(zo)*ftanh(cn);
        if (s == TT) out[(b0+bl2)*256 + 8*m + dl] = hn;
        else         stF(&whp[(b0+bl2)*256 + 8*m + dl], hn, l2);
      }
    }
    if (s == TT) break;
    tag_store(myB, s, l2);                  // covers h_s + wh_{s-1}
    if (s <= TT-2 && tid < 256) {           // slack: stage x_{s+1}
      const int bl = tid >> 6, d4 = (tid & 63) * 4;
      *(f32x4*)&sm[O_RACT + bl*S_RACT + ark(d4)] =
          *(const f32x4*)&x[((size_t)(b0+bl)*TT + s + 1)*DD + d4];
    }
  }
}

extern "C" void kernel_launch(void* const* d_in, const int* in_sizes, int n_in,
                              void* d_out, int out_size, void* d_ws, size_t ws_size,
                              hipStream_t stream) {
  (void)in_sizes; (void)n_in;
  if (ws_size < (size_t)WS_FLOATS * 4u) {   // loud failure instead of corruption
    hipMemsetAsync(d_out, 0, (size_t)out_size * 4u, stream);
    return;
  }
  const float* x  = (const float*)d_in[0];
  const float* rW = (const float*)d_in[1];
  const float* rU = (const float*)d_in[2];
  const float* rb = (const float*)d_in[3];
  const float* wW = (const float*)d_in[4];
  const float* wU = (const float*)d_in[5];
  const float* wb = (const float*)d_in[6];
  const float* cW = (const float*)d_in[7];
  const float* cb = (const float*)d_in[8];
  float* out = (float*)d_out;
  float* ws  = (float*)d_ws;

  hipFuncSetAttribute((const void*)nse_kernel,
                      hipFuncAttributeMaxDynamicSharedMemorySize, DYN_LDS_BYTES);

  void* args[] = { (void*)&x, (void*)&rW, (void*)&rU, (void*)&rb,
                   (void*)&wW, (void*)&wU, (void*)&wb, (void*)&cW, (void*)&cb,
                   (void*)&out, (void*)&ws };
  hipError_t err = hipLaunchCooperativeKernel((const void*)nse_kernel,
                                              dim3(256), dim3(TB), args,
                                              DYN_LDS_BYTES, stream);
  if (err != hipSuccess) {
    nse_kernel<<<dim3(256), dim3(TB), DYN_LDS_BYTES, stream>>>(
        x, rW, rU, rb, wW, wU, wb, cW, cb, out, ws);
  }
}